// Round 1
// baseline (727.421 us; speedup 1.0000x reference)
//
#include <hip/hip_runtime.h>

#define N_ROWS 65536
#define DIM 256
#define K_EMB 1024
#define LDS_STRIDE 132   // 128 + 4 pad: breaks bank conflicts on transposed staging writes

// ---------------- Kernel 0: half squared norms of emb rows (wave per row) --------
__global__ __launch_bounds__(256)
void halfnorm_kernel(const float* __restrict__ emb, float* __restrict__ hn,
                     float* __restrict__ loss_accum) {
    if (blockIdx.x == 0 && threadIdx.x == 0) loss_accum[0] = 0.0f;  // zero accumulator
    int wave = (blockIdx.x * blockDim.x + threadIdx.x) >> 6;
    int lane = threadIdx.x & 63;
    if (wave >= K_EMB) return;
    const float4* row = reinterpret_cast<const float4*>(emb + (size_t)wave * DIM);
    float4 v = row[lane];            // 64 lanes x float4 = 256 elems
    float s = v.x * v.x + v.y * v.y + v.z * v.z + v.w * v.w;
    #pragma unroll
    for (int off = 32; off > 0; off >>= 1) s += __shfl_xor(s, off, 64);
    if (lane == 0) hn[wave] = 0.5f * s;
}

// ---------------- Kernel 1: fused GEMM + row argmax ------------------------------
// score[n][k] = x_n . e_k - 0.5*||e_k||^2 ; argmax_k == argmin_k distance
// Block: 128 rows, loops over all 1024 cols in tiles of 128. 256 threads, 8x8 micro-tile.
__global__ __launch_bounds__(256, 2)
void argmax_kernel(const float* __restrict__ x, const float* __restrict__ emb,
                   const float* __restrict__ hn, int* __restrict__ out_idx) {
    __shared__ float xs[32 * LDS_STRIDE];   // x tile, transposed: xs[d][row]
    __shared__ float es[32 * LDS_STRIDE];   // e tile, transposed: es[d][col]
    __shared__ float red_s[16][16][8];
    __shared__ int   red_i[16][16][8];

    const int t  = threadIdx.x;
    const int tx = t & 15;   // col group
    const int ty = t >> 4;   // row group
    const int n0 = blockIdx.x * 128;

    float best[8];
    int   bidx[8];
    #pragma unroll
    for (int i = 0; i < 8; ++i) { best[i] = -1e30f; bidx[i] = 0; }

    for (int kt = 0; kt < K_EMB; kt += 128) {
        float acc[8][8];
        #pragma unroll
        for (int i = 0; i < 8; ++i)
            #pragma unroll
            for (int j = 0; j < 8; ++j) acc[i][j] = 0.0f;

        for (int d0 = 0; d0 < DIM; d0 += 32) {
            __syncthreads();   // protect LDS reuse from previous chunk
            // stage 128x32 tiles of x and emb, transposed into LDS
            #pragma unroll
            for (int i = 0; i < 4; ++i) {
                int f   = t + i * 256;        // 1024 float4 slots
                int row = f >> 3;             // 0..127
                int c4  = f & 7;              // 0..7 (float4 within 32-wide d chunk)
                float4 v = *reinterpret_cast<const float4*>(
                    x + (size_t)(n0 + row) * DIM + d0 + c4 * 4);
                xs[(c4 * 4 + 0) * LDS_STRIDE + row] = v.x;
                xs[(c4 * 4 + 1) * LDS_STRIDE + row] = v.y;
                xs[(c4 * 4 + 2) * LDS_STRIDE + row] = v.z;
                xs[(c4 * 4 + 3) * LDS_STRIDE + row] = v.w;
                float4 w = *reinterpret_cast<const float4*>(
                    emb + (size_t)(kt + row) * DIM + d0 + c4 * 4);
                es[(c4 * 4 + 0) * LDS_STRIDE + row] = w.x;
                es[(c4 * 4 + 1) * LDS_STRIDE + row] = w.y;
                es[(c4 * 4 + 2) * LDS_STRIDE + row] = w.z;
                es[(c4 * 4 + 3) * LDS_STRIDE + row] = w.w;
            }
            __syncthreads();
            // compute: 32 d-steps, 64 FMAs each
            #pragma unroll
            for (int d = 0; d < 32; ++d) {
                const float* xr = xs + d * LDS_STRIDE;
                const float* er = es + d * LDS_STRIDE;
                float4 a0 = *reinterpret_cast<const float4*>(xr + ty * 4);
                float4 a1 = *reinterpret_cast<const float4*>(xr + 64 + ty * 4);
                float4 b0 = *reinterpret_cast<const float4*>(er + tx * 4);
                float4 b1 = *reinterpret_cast<const float4*>(er + 64 + tx * 4);
                float av[8] = {a0.x, a0.y, a0.z, a0.w, a1.x, a1.y, a1.z, a1.w};
                float bv[8] = {b0.x, b0.y, b0.z, b0.w, b1.x, b1.y, b1.z, b1.w};
                #pragma unroll
                for (int i = 0; i < 8; ++i)
                    #pragma unroll
                    for (int j = 0; j < 8; ++j)
                        acc[i][j] += av[i] * bv[j];
            }
        }
        // fold in -0.5*||e||^2 and update running argmax (lower index wins ties)
        #pragma unroll
        for (int j = 0; j < 8; ++j) {
            int k = kt + ((j < 4) ? (tx * 4 + j) : (64 + tx * 4 + (j - 4)));
            float h = hn[k];
            #pragma unroll
            for (int i = 0; i < 8; ++i) {
                float s = acc[i][j] - h;
                if (s > best[i] || (s == best[i] && k < bidx[i])) {
                    best[i] = s; bidx[i] = k;
                }
            }
        }
    }

    __syncthreads();
    #pragma unroll
    for (int i = 0; i < 8; ++i) { red_s[ty][tx][i] = best[i]; red_i[ty][tx][i] = bidx[i]; }
    __syncthreads();
    if (t < 128) {
        int r  = t;
        int rr = r & 63;
        int yy = rr >> 2;
        int ii = (rr & 3) + ((r >= 64) ? 4 : 0);
        float bs = red_s[yy][0][ii];
        int   bi = red_i[yy][0][ii];
        #pragma unroll
        for (int q = 1; q < 16; ++q) {
            float s  = red_s[yy][q][ii];
            int   kk = red_i[yy][q][ii];
            if (s > bs || (s == bs && kk < bi)) { bs = s; bi = kk; }
        }
        out_idx[n0 + r] = bi;
    }
}

// ---------------- Kernel 2: gather quantized + loss partial ----------------------
__global__ __launch_bounds__(256)
void gather_loss_kernel(const float* __restrict__ x, const float* __restrict__ emb,
                        const int* __restrict__ idx, float* __restrict__ out,
                        float* __restrict__ loss_accum) {
    int gid  = blockIdx.x * 256 + threadIdx.x;   // one float4 per thread
    int n    = gid >> 6;                          // 64 float4 per row
    int d4   = gid & 63;
    int k    = idx[n];                            // wave-uniform (one row per wave)
    float4 q  = *reinterpret_cast<const float4*>(emb + (size_t)k * DIM + d4 * 4);
    float4 xv = reinterpret_cast<const float4*>(x)[gid];
    reinterpret_cast<float4*>(out)[gid] = q;
    float dx = q.x - xv.x, dy = q.y - xv.y, dz = q.z - xv.z, dw = q.w - xv.w;
    float s = dx * dx + dy * dy + dz * dz + dw * dw;
    #pragma unroll
    for (int off = 32; off > 0; off >>= 1) s += __shfl_xor(s, off, 64);
    __shared__ float partial[4];
    int lane = threadIdx.x & 63;
    int wv   = threadIdx.x >> 6;
    if (lane == 0) partial[wv] = s;
    __syncthreads();
    if (threadIdx.x == 0)
        atomicAdd(loss_accum, partial[0] + partial[1] + partial[2] + partial[3]);
}

// ---------------- Kernel 3: finalize loss ---------------------------------------
__global__ void finalize_kernel(const float* __restrict__ loss_accum,
                                float* __restrict__ out_loss) {
    if (threadIdx.x == 0)
        out_loss[0] = 1.25f * loss_accum[0] / 16777216.0f;
}

extern "C" void kernel_launch(void* const* d_in, const int* in_sizes, int n_in,
                              void* d_out, int out_size, void* d_ws, size_t ws_size,
                              hipStream_t stream) {
    const float* x   = reinterpret_cast<const float*>(d_in[0]);
    const float* emb = reinterpret_cast<const float*>(d_in[1]);
    float* out       = reinterpret_cast<float*>(d_out);
    float* loss_out  = out + (size_t)N_ROWS * DIM;

    float* loss_accum = reinterpret_cast<float*>(d_ws);
    int*   idx        = reinterpret_cast<int*>((char*)d_ws + 256);
    float* hn         = reinterpret_cast<float*>((char*)d_ws + 256 + (size_t)N_ROWS * 4);

    halfnorm_kernel<<<K_EMB / 4, 256, 0, stream>>>(emb, hn, loss_accum);
    argmax_kernel<<<N_ROWS / 128, 256, 0, stream>>>(x, emb, hn, idx);
    gather_loss_kernel<<<(N_ROWS * DIM / 4) / 256, 256, 0, stream>>>(x, emb, idx, out, loss_accum);
    finalize_kernel<<<1, 64, 0, stream>>>(loss_accum, loss_out);
}

// Round 2
// 379.028 us; speedup vs baseline: 1.9192x; 1.9192x over previous
//
#include <hip/hip_runtime.h>

#define N_ROWS 65536
#define DIM 256
#define K_EMB 1024

typedef short bf16x8 __attribute__((ext_vector_type(8)));
typedef unsigned short ushort8_t __attribute__((ext_vector_type(8)));
typedef float f32x4 __attribute__((ext_vector_type(4)));

__device__ static inline unsigned short f2bf(float f) {
    unsigned int u = __float_as_uint(f);
    return (unsigned short)((u + 0x7fffu + ((u >> 16) & 1u)) >> 16);   // RNE
}

__device__ static inline void async16(const void* g, void* l) {
    __builtin_amdgcn_global_load_lds(
        (const __attribute__((address_space(1))) void*)g,
        (__attribute__((address_space(3))) void*)l, 16, 0, 0);
}

// ---------------- Kernel A: x fp32 -> bf16 (8 elems/thread) ----------------------
__global__ __launch_bounds__(256)
void convert_x_kernel(const float* __restrict__ x, unsigned short* __restrict__ xb) {
    int gid = blockIdx.x * 256 + threadIdx.x;
    const float4* p = reinterpret_cast<const float4*>(x) + (size_t)gid * 2;
    float4 a = p[0], b = p[1];
    ushort8_t v;
    v[0] = f2bf(a.x); v[1] = f2bf(a.y); v[2] = f2bf(a.z); v[3] = f2bf(a.w);
    v[4] = f2bf(b.x); v[5] = f2bf(b.y); v[6] = f2bf(b.z); v[7] = f2bf(b.w);
    *reinterpret_cast<ushort8_t*>(xb + (size_t)gid * 8) = v;
}

// ---------------- Kernel B: emb -> bf16 + half-norms + zero accum ---------------
__global__ __launch_bounds__(256)
void emb_prep_kernel(const float* __restrict__ emb, unsigned short* __restrict__ eb,
                     float* __restrict__ hn, float* __restrict__ loss_accum) {
    if (blockIdx.x == 0 && threadIdx.x == 0) loss_accum[0] = 0.0f;
    int wave = (blockIdx.x * 256 + threadIdx.x) >> 6;   // 1024 waves, one per emb row
    int lane = threadIdx.x & 63;
    float4 v = reinterpret_cast<const float4*>(emb + (size_t)wave * DIM)[lane];
    float s = v.x * v.x + v.y * v.y + v.z * v.z + v.w * v.w;
    #pragma unroll
    for (int off = 32; off > 0; off >>= 1) s += __shfl_xor(s, off, 64);
    if (lane == 0) hn[wave] = 0.5f * s;
    ushort4 w = { f2bf(v.x), f2bf(v.y), f2bf(v.z), f2bf(v.w) };
    *reinterpret_cast<ushort4*>(eb + (size_t)wave * DIM + lane * 4) = w;
}

// ---------------- Kernel C: MFMA score GEMM + fused row-argmax -------------------
// score[n][k] = x_n . e_k - 0.5||e_k||^2. Block: 128 rows x all 1024 cols
// (8 col-tiles of 128). 4 waves in 2x2; each wave 64x64 = 4x4 MFMA 16x16x32 tiles.
// LDS: A-chunk [0,8K) B-chunk [8K,16K) as (row,q)-packets of 8 bf16;
//      argmax-reduce overlays [0,33792); hn at [33792,37888).
__global__ __launch_bounds__(256, 2)
void argmax_mfma_kernel(const unsigned short* __restrict__ xb,
                        const unsigned short* __restrict__ eb,
                        const float* __restrict__ hn, int* __restrict__ out_idx) {
    __shared__ __align__(16) char smem[37888];
    float* redS = reinterpret_cast<float*>(smem);            // 128*33 f32
    int*   redI = reinterpret_cast<int*>(smem + 16896);      // 128*33 i32
    float* hns  = reinterpret_cast<float*>(smem + 33792);    // 1024 f32

    const int t    = threadIdx.x;
    const int w    = t >> 6, lane = t & 63;
    const int q    = lane >> 4, l15 = lane & 15;
    const int wr   = w >> 1,  wc  = w & 1;
    const int n0   = blockIdx.x * 128;

    for (int i = t; i < K_EMB; i += 256) hns[i] = hn[i];

    // staging packets: p = w*128 + issue*64 + lane ; packet p = (row=p>>2, k8=(p&3)*8)
    const int p0 = w * 128 + lane, p1 = p0 + 64;
    const int ar0 = p0 >> 2, ak0 = (p0 & 3) * 8;
    const int ar1 = p1 >> 2, ak1 = (p1 & 3) * 8;
    const unsigned short* xg0 = xb + (size_t)(n0 + ar0) * DIM + ak0;
    const unsigned short* xg1 = xb + (size_t)(n0 + ar1) * DIM + ak1;
    void* aL0 = smem + w * 2048;        void* aL1 = smem + w * 2048 + 1024;
    void* bL0 = smem + 8192 + w * 2048; void* bL1 = smem + 8192 + w * 2048 + 1024;

    // fragment LDS byte offsets: packet (row, q) at (row*4+q)*16
    int aoff[4], boff[4];
    #pragma unroll
    for (int mt = 0; mt < 4; ++mt) aoff[mt] = ((wr * 64 + mt * 16 + l15) * 4 + q) * 16;
    #pragma unroll
    for (int nt = 0; nt < 4; ++nt) boff[nt] = ((wc * 64 + nt * 16 + l15) * 4 + q) * 16;

    float best[16];
    int   bidx[16];
    #pragma unroll
    for (int i = 0; i < 16; ++i) { best[i] = -1e30f; bidx[i] = 0; }

    for (int kt = 0; kt < K_EMB; kt += 128) {
        f32x4 acc[4][4];
        #pragma unroll
        for (int mt = 0; mt < 4; ++mt)
            #pragma unroll
            for (int nt = 0; nt < 4; ++nt) acc[mt][nt] = (f32x4){0.f, 0.f, 0.f, 0.f};

        const unsigned short* eg0 = eb + (size_t)(kt + ar0) * DIM + ak0;
        const unsigned short* eg1 = eb + (size_t)(kt + ar1) * DIM + ak1;

        for (int d0 = 0; d0 < DIM; d0 += 32) {
            __syncthreads();                       // previous reads done before overwrite
            async16(xg0 + d0, aL0);
            async16(xg1 + d0, aL1);
            async16(eg0 + d0, bL0);
            async16(eg1 + d0, bL1);
            __syncthreads();                       // staged data visible (vmcnt drained)
            bf16x8 a[4], b[4];
            #pragma unroll
            for (int mt = 0; mt < 4; ++mt)
                a[mt] = *reinterpret_cast<const bf16x8*>(smem + aoff[mt]);
            #pragma unroll
            for (int nt = 0; nt < 4; ++nt)
                b[nt] = *reinterpret_cast<const bf16x8*>(smem + 8192 + boff[nt]);
            #pragma unroll
            for (int mt = 0; mt < 4; ++mt)
                #pragma unroll
                for (int nt = 0; nt < 4; ++nt)
                    acc[mt][nt] = __builtin_amdgcn_mfma_f32_16x16x32_bf16(
                        a[mt], b[nt], acc[mt][nt], 0, 0, 0);
        }
        // fused argmax epilogue for this 128-col tile (cols ascend per lane -> strict >)
        #pragma unroll
        for (int nt = 0; nt < 4; ++nt) {
            int k = kt + wc * 64 + nt * 16 + l15;
            float h = hns[k];
            #pragma unroll
            for (int mt = 0; mt < 4; ++mt)
                #pragma unroll
                for (int r = 0; r < 4; ++r) {
                    float s = acc[mt][nt][r] - h;
                    int slot = mt * 4 + r;
                    if (s > best[slot]) { best[slot] = s; bidx[slot] = k; }
                }
        }
    }

    __syncthreads();   // done with staging region; overlay reduce arrays
    #pragma unroll
    for (int mt = 0; mt < 4; ++mt)
        #pragma unroll
        for (int r = 0; r < 4; ++r) {
            int row  = wr * 64 + mt * 16 + q * 4 + r;
            int slot = wc * 16 + l15;
            redS[row * 33 + slot] = best[mt * 4 + r];
            redI[row * 33 + slot] = bidx[mt * 4 + r];
        }
    __syncthreads();
    if (t < 128) {
        float bs = redS[t * 33];
        int   bi = redI[t * 33];
        #pragma unroll
        for (int s = 1; s < 32; ++s) {
            float v  = redS[t * 33 + s];
            int   kk = redI[t * 33 + s];
            if (v > bs || (v == bs && kk < bi)) { bs = v; bi = kk; }
        }
        out_idx[n0 + t] = bi;
    }
}

// ---------------- Kernel D: gather quantized + loss partial ----------------------
__global__ __launch_bounds__(256)
void gather_loss_kernel(const float* __restrict__ x, const float* __restrict__ emb,
                        const int* __restrict__ idx, float* __restrict__ out,
                        float* __restrict__ loss_accum) {
    int gid = blockIdx.x * 256 + threadIdx.x;   // one float4 per thread
    int n   = gid >> 6;                          // row per wave (uniform)
    int d4  = gid & 63;
    int k   = idx[n];
    float4 qv = *reinterpret_cast<const float4*>(emb + (size_t)k * DIM + d4 * 4);
    float4 xv = reinterpret_cast<const float4*>(x)[gid];
    reinterpret_cast<float4*>(out)[gid] = qv;
    float dx = qv.x - xv.x, dy = qv.y - xv.y, dz = qv.z - xv.z, dw = qv.w - xv.w;
    float s = dx * dx + dy * dy + dz * dz + dw * dw;
    #pragma unroll
    for (int off = 32; off > 0; off >>= 1) s += __shfl_xor(s, off, 64);
    __shared__ float partial[4];
    int lane = threadIdx.x & 63, wv = threadIdx.x >> 6;
    if (lane == 0) partial[wv] = s;
    __syncthreads();
    if (threadIdx.x == 0)
        atomicAdd(loss_accum, partial[0] + partial[1] + partial[2] + partial[3]);
}

// ---------------- Kernel E: finalize loss ---------------------------------------
__global__ void finalize_kernel(const float* __restrict__ loss_accum,
                                float* __restrict__ out_loss) {
    if (threadIdx.x == 0)
        out_loss[0] = 1.25f * loss_accum[0] / 16777216.0f;
}

extern "C" void kernel_launch(void* const* d_in, const int* in_sizes, int n_in,
                              void* d_out, int out_size, void* d_ws, size_t ws_size,
                              hipStream_t stream) {
    const float* x   = reinterpret_cast<const float*>(d_in[0]);
    const float* emb = reinterpret_cast<const float*>(d_in[1]);
    float* out       = reinterpret_cast<float*>(d_out);
    float* loss_out  = out + (size_t)N_ROWS * DIM;

    char* ws = reinterpret_cast<char*>(d_ws);
    float*          loss_accum = reinterpret_cast<float*>(ws);                 // 256 B
    float*          hn         = reinterpret_cast<float*>(ws + 4096);          // 4 KB
    int*            idx        = reinterpret_cast<int*>(ws + 8192);            // 256 KB
    unsigned short* eb         = reinterpret_cast<unsigned short*>(ws + 524288);    // 512 KB
    unsigned short* xb         = reinterpret_cast<unsigned short*>(ws + 1048576);   // 32 MB

    convert_x_kernel<<<N_ROWS * DIM / 8 / 256, 256, 0, stream>>>(x, xb);
    emb_prep_kernel<<<K_EMB / 4, 256, 0, stream>>>(emb, eb, hn, loss_accum);
    argmax_mfma_kernel<<<N_ROWS / 128, 256, 0, stream>>>(xb, eb, hn, idx);
    gather_loss_kernel<<<(N_ROWS * DIM / 4) / 256, 256, 0, stream>>>(x, emb, idx, out, loss_accum);
    finalize_kernel<<<1, 64, 0, stream>>>(loss_accum, loss_out);
}

// Round 3
// 197.852 us; speedup vs baseline: 3.6766x; 1.9157x over previous
//
#include <hip/hip_runtime.h>

#define N_ROWS 65536
#define DIM 256
#define K_EMB 1024

typedef short bf16x8 __attribute__((ext_vector_type(8)));
typedef unsigned short ushort8_t __attribute__((ext_vector_type(8)));
typedef float f32x4 __attribute__((ext_vector_type(4)));

__device__ static inline unsigned short f2bf(float f) {
    unsigned int u = __float_as_uint(f);
    return (unsigned short)((u + 0x7fffu + ((u >> 16) & 1u)) >> 16);   // RNE
}

__device__ static inline void async16(const void* g, void* l) {
    __builtin_amdgcn_global_load_lds(
        (const __attribute__((address_space(1))) void*)g,
        (__attribute__((address_space(3))) void*)l, 16, 0, 0);
}

// ---------------- Kernel A: x fp32 -> bf16 (8 elems/thread) ----------------------
__global__ __launch_bounds__(256)
void convert_x_kernel(const float* __restrict__ x, unsigned short* __restrict__ xb) {
    int gid = blockIdx.x * 256 + threadIdx.x;
    const float4* p = reinterpret_cast<const float4*>(x) + (size_t)gid * 2;
    float4 a = p[0], b = p[1];
    ushort8_t v;
    v[0] = f2bf(a.x); v[1] = f2bf(a.y); v[2] = f2bf(a.z); v[3] = f2bf(a.w);
    v[4] = f2bf(b.x); v[5] = f2bf(b.y); v[6] = f2bf(b.z); v[7] = f2bf(b.w);
    *reinterpret_cast<ushort8_t*>(xb + (size_t)gid * 8) = v;
}

// ---------------- Kernel B: emb -> bf16 + half-norms + zero accum ---------------
__global__ __launch_bounds__(256)
void emb_prep_kernel(const float* __restrict__ emb, unsigned short* __restrict__ eb,
                     float* __restrict__ hn, float* __restrict__ loss_accum) {
    if (blockIdx.x == 0 && threadIdx.x == 0) loss_accum[0] = 0.0f;
    int wave = (blockIdx.x * 256 + threadIdx.x) >> 6;   // 1024 waves, one per emb row
    int lane = threadIdx.x & 63;
    float4 v = reinterpret_cast<const float4*>(emb + (size_t)wave * DIM)[lane];
    float s = v.x * v.x + v.y * v.y + v.z * v.z + v.w * v.w;
    #pragma unroll
    for (int off = 32; off > 0; off >>= 1) s += __shfl_xor(s, off, 64);
    if (lane == 0) hn[wave] = 0.5f * s;
    ushort4 w = { f2bf(v.x), f2bf(v.y), f2bf(v.z), f2bf(v.w) };
    *reinterpret_cast<ushort4*>(eb + (size_t)wave * DIM + lane * 4) = w;
}

// ---------------- Kernel C: MFMA score GEMM + fused row-argmax -------------------
// score[n][k] = x_n . e_k - 0.5||e_k||^2. Block: 128 rows x all 1024 cols
// (8 col-tiles of 128). 4 waves in 2x2; each wave 64x64 = 4x4 MFMA 16x16x32 tiles.
__global__ __launch_bounds__(256, 2)
void argmax_mfma_kernel(const unsigned short* __restrict__ xb,
                        const unsigned short* __restrict__ eb,
                        const float* __restrict__ hn, int* __restrict__ out_idx) {
    __shared__ __align__(16) char smem[37888];
    float* redS = reinterpret_cast<float*>(smem);            // 128*33 f32
    int*   redI = reinterpret_cast<int*>(smem + 16896);      // 128*33 i32
    float* hns  = reinterpret_cast<float*>(smem + 33792);    // 1024 f32

    const int t    = threadIdx.x;
    const int w    = t >> 6, lane = t & 63;
    const int q    = lane >> 4, l15 = lane & 15;
    const int wr   = w >> 1,  wc  = w & 1;
    const int n0   = blockIdx.x * 128;

    for (int i = t; i < K_EMB; i += 256) hns[i] = hn[i];

    // staging packets: p = w*128 + issue*64 + lane ; packet p = (row=p>>2, k8=(p&3)*8)
    const int p0 = w * 128 + lane, p1 = p0 + 64;
    const int ar0 = p0 >> 2, ak0 = (p0 & 3) * 8;
    const int ar1 = p1 >> 2, ak1 = (p1 & 3) * 8;
    const unsigned short* xg0 = xb + (size_t)(n0 + ar0) * DIM + ak0;
    const unsigned short* xg1 = xb + (size_t)(n0 + ar1) * DIM + ak1;
    void* aL0 = smem + w * 2048;        void* aL1 = smem + w * 2048 + 1024;
    void* bL0 = smem + 8192 + w * 2048; void* bL1 = smem + 8192 + w * 2048 + 1024;

    // fragment LDS byte offsets: packet (row, q) at (row*4+q)*16
    int aoff[4], boff[4];
    #pragma unroll
    for (int mt = 0; mt < 4; ++mt) aoff[mt] = ((wr * 64 + mt * 16 + l15) * 4 + q) * 16;
    #pragma unroll
    for (int nt = 0; nt < 4; ++nt) boff[nt] = ((wc * 64 + nt * 16 + l15) * 4 + q) * 16;

    float best[16];
    int   bidx[16];
    #pragma unroll
    for (int i = 0; i < 16; ++i) { best[i] = -1e30f; bidx[i] = 0; }

    for (int kt = 0; kt < K_EMB; kt += 128) {
        f32x4 acc[4][4];
        #pragma unroll
        for (int mt = 0; mt < 4; ++mt)
            #pragma unroll
            for (int nt = 0; nt < 4; ++nt) acc[mt][nt] = (f32x4){0.f, 0.f, 0.f, 0.f};

        const unsigned short* eg0 = eb + (size_t)(kt + ar0) * DIM + ak0;
        const unsigned short* eg1 = eb + (size_t)(kt + ar1) * DIM + ak1;

        for (int d0 = 0; d0 < DIM; d0 += 32) {
            __syncthreads();                       // previous reads done before overwrite
            async16(xg0 + d0, aL0);
            async16(xg1 + d0, aL1);
            async16(eg0 + d0, bL0);
            async16(eg1 + d0, bL1);
            __syncthreads();                       // staged data visible (vmcnt drained)
            bf16x8 a[4], b[4];
            #pragma unroll
            for (int mt = 0; mt < 4; ++mt)
                a[mt] = *reinterpret_cast<const bf16x8*>(smem + aoff[mt]);
            #pragma unroll
            for (int nt = 0; nt < 4; ++nt)
                b[nt] = *reinterpret_cast<const bf16x8*>(smem + 8192 + boff[nt]);
            #pragma unroll
            for (int mt = 0; mt < 4; ++mt)
                #pragma unroll
                for (int nt = 0; nt < 4; ++nt)
                    acc[mt][nt] = __builtin_amdgcn_mfma_f32_16x16x32_bf16(
                        a[mt], b[nt], acc[mt][nt], 0, 0, 0);
        }
        // fused argmax epilogue for this 128-col tile (cols ascend per lane -> strict >)
        #pragma unroll
        for (int nt = 0; nt < 4; ++nt) {
            int k = kt + wc * 64 + nt * 16 + l15;
            float h = hns[k];
            #pragma unroll
            for (int mt = 0; mt < 4; ++mt)
                #pragma unroll
                for (int r = 0; r < 4; ++r) {
                    float s = acc[mt][nt][r] - h;
                    int slot = mt * 4 + r;
                    if (s > best[slot]) { best[slot] = s; bidx[slot] = k; }
                }
        }
    }

    __syncthreads();   // done with staging region; overlay reduce arrays
    #pragma unroll
    for (int mt = 0; mt < 4; ++mt)
        #pragma unroll
        for (int r = 0; r < 4; ++r) {
            int row  = wr * 64 + mt * 16 + q * 4 + r;
            int slot = wc * 16 + l15;
            redS[row * 33 + slot] = best[mt * 4 + r];
            redI[row * 33 + slot] = bidx[mt * 4 + r];
        }
    __syncthreads();
    if (t < 128) {
        float bs = redS[t * 33];
        int   bi = redI[t * 33];
        #pragma unroll
        for (int s = 1; s < 32; ++s) {
            float v  = redS[t * 33 + s];
            int   kk = redI[t * 33 + s];
            if (v > bs || (v == bs && kk < bi)) { bs = v; bi = kk; }
        }
        out_idx[n0 + t] = bi;
    }
}

// ---------------- Kernel D: gather quantized + loss (grid-stride) ---------------
// 1024 blocks x 256 threads; 16 float4-iterations/thread; ONE atomic per block.
#define GL_BLOCKS 1024
__global__ __launch_bounds__(256)
void gather_loss_kernel(const float* __restrict__ x, const float* __restrict__ emb,
                        const int* __restrict__ idx, float* __restrict__ out,
                        float* __restrict__ loss_accum) {
    const int total = N_ROWS * DIM / 4;   // 4,194,304 float4
    float s = 0.0f;
    for (int gid = blockIdx.x * 256 + threadIdx.x; gid < total; gid += GL_BLOCKS * 256) {
        int n  = gid >> 6;                // row per wave-iteration (uniform in wave)
        int d4 = gid & 63;
        int k  = idx[n];
        float4 qv = *reinterpret_cast<const float4*>(emb + (size_t)k * DIM + d4 * 4);
        float4 xv = reinterpret_cast<const float4*>(x)[gid];
        reinterpret_cast<float4*>(out)[gid] = qv;
        float dx = qv.x - xv.x, dy = qv.y - xv.y, dz = qv.z - xv.z, dw = qv.w - xv.w;
        s += dx * dx + dy * dy + dz * dz + dw * dw;
    }
    #pragma unroll
    for (int off = 32; off > 0; off >>= 1) s += __shfl_xor(s, off, 64);
    __shared__ float partial[4];
    int lane = threadIdx.x & 63, wv = threadIdx.x >> 6;
    if (lane == 0) partial[wv] = s;
    __syncthreads();
    if (threadIdx.x == 0)
        atomicAdd(loss_accum, partial[0] + partial[1] + partial[2] + partial[3]);
}

// ---------------- Kernel E: finalize loss ---------------------------------------
__global__ void finalize_kernel(const float* __restrict__ loss_accum,
                                float* __restrict__ out_loss) {
    if (threadIdx.x == 0)
        out_loss[0] = 1.25f * loss_accum[0] / 16777216.0f;
}

extern "C" void kernel_launch(void* const* d_in, const int* in_sizes, int n_in,
                              void* d_out, int out_size, void* d_ws, size_t ws_size,
                              hipStream_t stream) {
    const float* x   = reinterpret_cast<const float*>(d_in[0]);
    const float* emb = reinterpret_cast<const float*>(d_in[1]);
    float* out       = reinterpret_cast<float*>(d_out);
    float* loss_out  = out + (size_t)N_ROWS * DIM;

    char* ws = reinterpret_cast<char*>(d_ws);
    float*          loss_accum = reinterpret_cast<float*>(ws);                 // 256 B
    float*          hn         = reinterpret_cast<float*>(ws + 4096);          // 4 KB
    int*            idx        = reinterpret_cast<int*>(ws + 8192);            // 256 KB
    unsigned short* eb         = reinterpret_cast<unsigned short*>(ws + 524288);    // 512 KB
    unsigned short* xb         = reinterpret_cast<unsigned short*>(ws + 1048576);   // 32 MB

    convert_x_kernel<<<N_ROWS * DIM / 8 / 256, 256, 0, stream>>>(x, xb);
    emb_prep_kernel<<<K_EMB / 4, 256, 0, stream>>>(emb, eb, hn, loss_accum);
    argmax_mfma_kernel<<<N_ROWS / 128, 256, 0, stream>>>(xb, eb, hn, idx);
    gather_loss_kernel<<<GL_BLOCKS, 256, 0, stream>>>(x, emb, idx, out, loss_accum);
    finalize_kernel<<<1, 64, 0, stream>>>(loss_accum, loss_out);
}

// Round 4
// 177.477 us; speedup vs baseline: 4.0987x; 1.1148x over previous
//
#include <hip/hip_runtime.h>

#define N_ROWS 65536
#define DIM 256
#define K_EMB 1024

typedef short bf16x8 __attribute__((ext_vector_type(8)));
typedef unsigned short ushort8_t __attribute__((ext_vector_type(8)));
typedef float f32x4 __attribute__((ext_vector_type(4)));

__device__ static inline unsigned short f2bf(float f) {
    unsigned int u = __float_as_uint(f);
    return (unsigned short)((u + 0x7fffu + ((u >> 16) & 1u)) >> 16);   // RNE
}

__device__ static inline void async16(const void* g, void* l) {
    __builtin_amdgcn_global_load_lds(
        (const __attribute__((address_space(1))) void*)g,
        (__attribute__((address_space(3))) void*)l, 16, 0, 0);
}

// ---------------- Kernel A: x fp32 -> bf16 (8 elems/thread) ----------------------
__global__ __launch_bounds__(256)
void convert_x_kernel(const float* __restrict__ x, unsigned short* __restrict__ xb) {
    int gid = blockIdx.x * 256 + threadIdx.x;
    const float4* p = reinterpret_cast<const float4*>(x) + (size_t)gid * 2;
    float4 a = p[0], b = p[1];
    ushort8_t v;
    v[0] = f2bf(a.x); v[1] = f2bf(a.y); v[2] = f2bf(a.z); v[3] = f2bf(a.w);
    v[4] = f2bf(b.x); v[5] = f2bf(b.y); v[6] = f2bf(b.z); v[7] = f2bf(b.w);
    *reinterpret_cast<ushort8_t*>(xb + (size_t)gid * 8) = v;
}

// ---------------- Kernel B: emb -> bf16 + half-norms + zero accum ---------------
__global__ __launch_bounds__(256)
void emb_prep_kernel(const float* __restrict__ emb, unsigned short* __restrict__ eb,
                     float* __restrict__ hn, float* __restrict__ loss_accum) {
    if (blockIdx.x == 0 && threadIdx.x == 0) loss_accum[0] = 0.0f;
    int wave = (blockIdx.x * 256 + threadIdx.x) >> 6;   // 1024 waves, one per emb row
    int lane = threadIdx.x & 63;
    float4 v = reinterpret_cast<const float4*>(emb + (size_t)wave * DIM)[lane];
    float s = v.x * v.x + v.y * v.y + v.z * v.z + v.w * v.w;
    #pragma unroll
    for (int off = 32; off > 0; off >>= 1) s += __shfl_xor(s, off, 64);
    if (lane == 0) hn[wave] = 0.5f * s;
    ushort4 w = { f2bf(v.x), f2bf(v.y), f2bf(v.z), f2bf(v.w) };
    *reinterpret_cast<ushort4*>(eb + (size_t)wave * DIM + lane * 4) = w;
}

// ---------------- Kernel C: MFMA score GEMM + fused row-argmax -------------------
// Block: 128 rows x ALL 1024 cols. 4 waves, 32 rows/wave, A (K=256) in registers.
// B swept in 16 chunks of 64 cols, double-buffered via global_load_lds prefetch.
// acc init = -0.5||e||^2 so epilogue is a single compare per score.
// LDS: bufs [0,32K)+[32K,64K) (A staged across both at startup); hn [64K,68K).
__global__ __launch_bounds__(256, 2)
void argmax_mfma_kernel(const unsigned short* __restrict__ xb,
                        const unsigned short* __restrict__ eb,
                        const float* __restrict__ hn, int* __restrict__ out_idx) {
    __shared__ __align__(16) char smem[69632];
    float* hns = reinterpret_cast<float*>(smem + 65536);

    const int t    = threadIdx.x;
    const int w    = t >> 6, lane = t & 63;
    const int q    = lane >> 4, l15 = lane & 15;
    const int n0   = blockIdx.x * 128;

    #pragma unroll
    for (int i = 0; i < 4; ++i) hns[t + i * 256] = hn[t + i * 256];

    // ---- stage A: 128 rows x 256 d bf16 = 64KB, XOR-swizzled packets ----
    #pragma unroll
    for (int i = 0; i < 16; ++i) {
        int s   = i * 256 + t;
        int row = s >> 5;
        int pk  = (s & 24) | ((s ^ row) & 7);
        async16(xb + (size_t)(n0 + row) * DIM + pk * 8,
                smem + (i * 256 + w * 64) * 16);
    }
    __syncthreads();   // A staged (vmcnt drained at barrier)

    // ---- A fragments to registers: 2 m-tiles x 8 k-steps ----
    bf16x8 a[2][8];
    #pragma unroll
    for (int mt = 0; mt < 2; ++mt) {
        int row = w * 32 + mt * 16 + l15;
        #pragma unroll
        for (int ks = 0; ks < 8; ++ks) {
            int pk  = ks * 4 + q;
            int swz = (pk & 24) | ((pk ^ row) & 7);
            a[mt][ks] = *reinterpret_cast<const bf16x8*>(smem + row * 512 + swz * 16);
        }
    }
    __syncthreads();   // everyone done reading A region; B staging may overwrite

    // ---- per-thread B staging constants (swizzled) ----
    const unsigned short* egp[4];
    int ldsB[4];
    #pragma unroll
    for (int i = 0; i < 4; ++i) {
        int s  = i * 512 + t;
        int c  = s >> 5;
        int pk = (s & 24) | ((s ^ c) & 7);
        egp[i]  = eb + (size_t)c * DIM + pk * 8;
        ldsB[i] = (i * 512 + w * 64) * 16;
    }
    // B-frag LDS offsets: col stride 512B; swizzle depends only on l15 (c&7==l15&7)
    int soff[8];
    #pragma unroll
    for (int ks = 0; ks < 8; ++ks) {
        int pk = ks * 4 + q;
        soff[ks] = ((pk & 24) | ((pk ^ l15) & 7)) * 16;
    }
    int cb[4];
    #pragma unroll
    for (int nt = 0; nt < 4; ++nt) cb[nt] = (nt * 16 + l15) * 512;

    float best[8];
    int   bidx[8];
    #pragma unroll
    for (int i = 0; i < 8; ++i) { best[i] = -1e30f; bidx[i] = 0; }

    // prefetch chunk 0 -> buf0
    #pragma unroll
    for (int i = 0; i < 4; ++i) async16(egp[i], smem + ldsB[i]);

    for (int c = 0; c < 16; ++c) {
        __syncthreads();   // chunk c staged; prior readers of other buf done
        const char* buf = smem + (c & 1) * 32768;
        if (c < 15) {      // prefetch chunk c+1 into the buffer freed at the barrier
            int nb = ((c + 1) & 1) * 32768;
            #pragma unroll
            for (int i = 0; i < 4; ++i)
                async16(egp[i] + (c + 1) * 64 * DIM, smem + nb + ldsB[i]);
        }
        f32x4 acc[2][4];
        #pragma unroll
        for (int nt = 0; nt < 4; ++nt) {
            float h = -hns[c * 64 + nt * 16 + l15];
            f32x4 in4 = {h, h, h, h};
            acc[0][nt] = in4; acc[1][nt] = in4;
        }
        #pragma unroll
        for (int ks = 0; ks < 8; ++ks) {
            bf16x8 b0 = *reinterpret_cast<const bf16x8*>(buf + cb[0] + soff[ks]);
            bf16x8 b1 = *reinterpret_cast<const bf16x8*>(buf + cb[1] + soff[ks]);
            bf16x8 b2 = *reinterpret_cast<const bf16x8*>(buf + cb[2] + soff[ks]);
            bf16x8 b3 = *reinterpret_cast<const bf16x8*>(buf + cb[3] + soff[ks]);
            acc[0][0] = __builtin_amdgcn_mfma_f32_16x16x32_bf16(a[0][ks], b0, acc[0][0], 0, 0, 0);
            acc[1][0] = __builtin_amdgcn_mfma_f32_16x16x32_bf16(a[1][ks], b0, acc[1][0], 0, 0, 0);
            acc[0][1] = __builtin_amdgcn_mfma_f32_16x16x32_bf16(a[0][ks], b1, acc[0][1], 0, 0, 0);
            acc[1][1] = __builtin_amdgcn_mfma_f32_16x16x32_bf16(a[1][ks], b1, acc[1][1], 0, 0, 0);
            acc[0][2] = __builtin_amdgcn_mfma_f32_16x16x32_bf16(a[0][ks], b2, acc[0][2], 0, 0, 0);
            acc[1][2] = __builtin_amdgcn_mfma_f32_16x16x32_bf16(a[1][ks], b2, acc[1][2], 0, 0, 0);
            acc[0][3] = __builtin_amdgcn_mfma_f32_16x16x32_bf16(a[0][ks], b3, acc[0][3], 0, 0, 0);
            acc[1][3] = __builtin_amdgcn_mfma_f32_16x16x32_bf16(a[1][ks], b3, acc[1][3], 0, 0, 0);
        }
        // epilogue: scores already include -0.5||e||^2; cols ascend -> strict >
        #pragma unroll
        for (int nt = 0; nt < 4; ++nt) {
            int k = c * 64 + nt * 16 + l15;
            #pragma unroll
            for (int mt = 0; mt < 2; ++mt)
                #pragma unroll
                for (int r = 0; r < 4; ++r) {
                    float sc = acc[mt][nt][r];
                    int slot = mt * 4 + r;
                    if (sc > best[slot]) { best[slot] = sc; bidx[slot] = k; }
                }
        }
    }

    // butterfly argmax across the 16 l15 lanes (lowest index wins ties)
    #pragma unroll
    for (int slot = 0; slot < 8; ++slot) {
        float bs = best[slot]; int bi = bidx[slot];
        #pragma unroll
        for (int off = 8; off >= 1; off >>= 1) {
            float os = __shfl_xor(bs, off, 64);
            int   oi = __shfl_xor(bi, off, 64);
            if (os > bs || (os == bs && oi < bi)) { bs = os; bi = oi; }
        }
        if (l15 == 0) {
            int mt = slot >> 2, r = slot & 3;
            out_idx[n0 + w * 32 + mt * 16 + q * 4 + r] = bi;
        }
    }
}

// ---------------- Kernel D: gather quantized + loss (16 rows/wave, unrolled) -----
#define GL_BLOCKS 1024
__global__ __launch_bounds__(256)
void gather_loss_kernel(const float* __restrict__ x, const float* __restrict__ emb,
                        const int* __restrict__ idx, float* __restrict__ out,
                        float* __restrict__ loss_accum) {
    int wv   = blockIdx.x * 4 + (threadIdx.x >> 6);   // 4096 waves
    int lane = threadIdx.x & 63;
    int r0   = wv * 16;                                // 16 rows per wave
    float s  = 0.0f;
    #pragma unroll
    for (int i = 0; i < 16; ++i) {
        int n = r0 + i;
        int k = idx[n];
        float4 qv = *reinterpret_cast<const float4*>(emb + (size_t)k * DIM + lane * 4);
        float4 xv = *reinterpret_cast<const float4*>(x + (size_t)n * DIM + lane * 4);
        *reinterpret_cast<float4*>(out + (size_t)n * DIM + lane * 4) = qv;
        float dx = qv.x - xv.x, dy = qv.y - xv.y, dz = qv.z - xv.z, dw = qv.w - xv.w;
        s += dx * dx + dy * dy + dz * dz + dw * dw;
    }
    #pragma unroll
    for (int off = 32; off > 0; off >>= 1) s += __shfl_xor(s, off, 64);
    __shared__ float partial[4];
    int lid = threadIdx.x & 63, wvl = threadIdx.x >> 6;
    if (lid == 0) partial[wvl] = s;
    __syncthreads();
    if (threadIdx.x == 0)
        atomicAdd(loss_accum, partial[0] + partial[1] + partial[2] + partial[3]);
}

// ---------------- Kernel E: finalize loss ---------------------------------------
__global__ void finalize_kernel(const float* __restrict__ loss_accum,
                                float* __restrict__ out_loss) {
    if (threadIdx.x == 0)
        out_loss[0] = 1.25f * loss_accum[0] / 16777216.0f;
}

extern "C" void kernel_launch(void* const* d_in, const int* in_sizes, int n_in,
                              void* d_out, int out_size, void* d_ws, size_t ws_size,
                              hipStream_t stream) {
    const float* x   = reinterpret_cast<const float*>(d_in[0]);
    const float* emb = reinterpret_cast<const float*>(d_in[1]);
    float* out       = reinterpret_cast<float*>(d_out);
    float* loss_out  = out + (size_t)N_ROWS * DIM;

    char* ws = reinterpret_cast<char*>(d_ws);
    float*          loss_accum = reinterpret_cast<float*>(ws);                 // 256 B
    float*          hn         = reinterpret_cast<float*>(ws + 4096);          // 4 KB
    int*            idx        = reinterpret_cast<int*>(ws + 8192);            // 256 KB
    unsigned short* eb         = reinterpret_cast<unsigned short*>(ws + 524288);    // 512 KB
    unsigned short* xb         = reinterpret_cast<unsigned short*>(ws + 1048576);   // 32 MB

    convert_x_kernel<<<N_ROWS * DIM / 8 / 256, 256, 0, stream>>>(x, xb);
    emb_prep_kernel<<<K_EMB / 4, 256, 0, stream>>>(emb, eb, hn, loss_accum);
    argmax_mfma_kernel<<<N_ROWS / 128, 256, 0, stream>>>(xb, eb, hn, idx);
    gather_loss_kernel<<<GL_BLOCKS, 256, 0, stream>>>(x, emb, idx, out, loss_accum);
    finalize_kernel<<<1, 64, 0, stream>>>(loss_accum, loss_out);
}